// Round 1
// baseline (6179.594 us; speedup 1.0000x reference)
//
#include <hip/hip_runtime.h>
#include <hip/hip_bf16.h>
#include <stdint.h>

typedef __hip_bfloat16 bf16;
typedef __attribute__((ext_vector_type(8))) short bf16x8;
typedef __attribute__((ext_vector_type(4))) float f32x4;
typedef __attribute__((ext_vector_type(8))) unsigned short us8;

#define NB 8192
#define NE 256
#define NH 1024

__device__ __forceinline__ float bf2f(unsigned short u) {
  union { unsigned int i; float f; } x; x.i = ((unsigned int)u) << 16; return x.f;
}
__device__ __forceinline__ float sigm(float x) {
  return __builtin_amdgcn_rcpf(1.f + __expf(-x));
}
__device__ __forceinline__ float tanh_f(float x) {
  return 1.f - 2.f * __builtin_amdgcn_rcpf(1.f + __expf(2.f * x));
}

// ---------------- fused GEMM + LSTM cell ----------------
// gates = X@Wih^T + Hin@Whh^T + bias ; c' = sig(f)*c + sig(i)*tanh(g); h = sig(o)*tanh(c')
// Block: 128 M-rows x 32 h-cols (gate-N = 128 strided by 1024). 4 waves (2Mx2C).
// Wave n-fragments = the 4 gates -> epilogue fully in-register.
__global__ __launch_bounds__(256) void k_cell(
    const bf16* __restrict__ X, int ldx, int Kx,
    const bf16* __restrict__ Hin, int Kh,
    const bf16* __restrict__ Wih, const bf16* __restrict__ Whh,
    const float* __restrict__ bias, float* __restrict__ Cst,
    bf16* __restrict__ Hout, int czero)
{
  __shared__ bf16 As[2][128 * 64];
  __shared__ bf16 Ws[2][128 * 64];

  const int tid = threadIdx.x;
  const int l = tid & 63, w = tid >> 6;
  const int wr = w >> 1, wc = w & 1;

  // XCD-bijective swizzle (2048 blocks, 2048 % 8 == 0)
  const int bid = blockIdx.x;
  const int swz = (bid & 7) * 256 + (bid >> 3);
  const int m0 = (swz & 63) * 128;
  const int hc0 = (swz >> 6) * 32;

  const int NT = (Kx + Kh) >> 6;

  const int lr = l >> 3;  // 0..7 row within 8-row group
  const int lc = l & 7;   // 16B chunk id
  const int rbase = w * 32 + lr;

  f32x4 acc[4][4];
  f32x4 zero4 = {0.f, 0.f, 0.f, 0.f};
#pragma unroll
  for (int i = 0; i < 4; ++i)
#pragma unroll
    for (int j = 0; j < 4; ++j) acc[i][j] = zero4;

  const int koff = (l >> 4) * 16;
  const int sw = (l & 7) << 4;          // XOR swizzle (row&7)<<4 ; row&7 == l&7 here
  const int arow = wr * 64 + (l & 15);  // + mf*16
  const int wrow = wc * 16 + (l & 15);  // + g*32

  // stage K-tile kt into LDS buffer buf: linear LDS dest, inverse-swizzled global src
  auto stage = [&](int kt, int buf) {
    int kc = kt << 6;
    const bf16* ap; int lda; const bf16* wp; int ldw;
    if (kc < Kx) { ap = X; lda = ldx; wp = Wih; ldw = Kx; }
    else         { ap = Hin; lda = NH; wp = Whh; ldw = NH; kc -= Kx; }
#pragma unroll
    for (int i = 0; i < 4; ++i) {
      int r = rbase + i * 8;
      int ch = lc ^ (r & 7);
      const bf16* gp = ap + (size_t)(m0 + r) * lda + kc + ch * 8;
      __builtin_amdgcn_global_load_lds(
          (const __attribute__((address_space(1))) void*)gp,
          (__attribute__((address_space(3))) void*)(&As[buf][(w * 32 + i * 8) * 64]),
          16, 0, 0);
    }
#pragma unroll
    for (int i = 0; i < 4; ++i) {
      int r = rbase + i * 8;
      int wr2 = ((r >> 5) << 10) + hc0 + (r & 31);  // gate*1024 + hcol
      int ch = lc ^ (r & 7);
      const bf16* gp = wp + (size_t)wr2 * ldw + kc + ch * 8;
      __builtin_amdgcn_global_load_lds(
          (const __attribute__((address_space(1))) void*)gp,
          (__attribute__((address_space(3))) void*)(&Ws[buf][(w * 32 + i * 8) * 64]),
          16, 0, 0);
    }
  };

  stage(0, 0);
  __syncthreads();
  int cur = 0;
  for (int kt = 0; kt < NT; ++kt) {
    if (kt + 1 < NT) stage(kt + 1, cur ^ 1);
    const char* Ab = (const char*)&As[cur][0];
    const char* Wb = (const char*)&Ws[cur][0];
#pragma unroll
    for (int kk = 0; kk < 2; ++kk) {
      int off = (kk * 64 + koff) ^ sw;
      bf16x8 af[4], bfr[4];
#pragma unroll
      for (int mf = 0; mf < 4; ++mf)
        af[mf] = *(const bf16x8*)(Ab + (arow + mf * 16) * 128 + off);
#pragma unroll
      for (int g2 = 0; g2 < 4; ++g2)
        bfr[g2] = *(const bf16x8*)(Wb + (wrow + g2 * 32) * 128 + off);
#pragma unroll
      for (int mf = 0; mf < 4; ++mf)
#pragma unroll
        for (int g2 = 0; g2 < 4; ++g2)
          acc[mf][g2] = __builtin_amdgcn_mfma_f32_16x16x32_bf16(
              af[mf], bfr[g2], acc[mf][g2], 0, 0, 0);
    }
    __syncthreads();
    cur ^= 1;
  }

  // epilogue: acc[mf][gate][reg]; C/D layout col=lane&15, row=(lane>>4)*4+reg
  const int ecol = hc0 + wc * 16 + (l & 15);
  const float bi = bias[ecol];
  const float bf_ = bias[NH + ecol];
  const float bg = bias[2 * NH + ecol];
  const float bo = bias[3 * NH + ecol];
  const int r0 = m0 + wr * 64 + ((l >> 4) << 2);
#pragma unroll
  for (int mf = 0; mf < 4; ++mf) {
#pragma unroll
    for (int r = 0; r < 4; ++r) {
      int row = r0 + mf * 16 + r;
      size_t idx = (size_t)row * NH + ecol;
      float gi = sigm(acc[mf][0][r] + bi);
      float gf = sigm(acc[mf][1][r] + bf_);
      float gg = tanh_f(acc[mf][2][r] + bg);
      float go = sigm(acc[mf][3][r] + bo);
      float cold = czero ? 0.f : Cst[idx];
      float cn = gf * cold + gi * gg;
      Cst[idx] = cn;
      Hout[idx] = __float2bfloat16(go * tanh_f(cn));
    }
  }
}

// ---------------- MLP decode head + displacement add + re-embed ----------------
// one wave per batch row
__global__ __launch_bounds__(256) void k_mlp(
    const bf16* __restrict__ h1, const bf16* __restrict__ W1b, const float* __restrict__ b1,
    const float* __restrict__ W2, const float* __restrict__ b2,
    const float* __restrict__ W3, const float* __restrict__ b3,
    const float* __restrict__ cin, float* __restrict__ cout,
    float* __restrict__ preds, const float* __restrict__ Wemb,
    const float* __restrict__ bemb, bf16* __restrict__ embout)
{
  const int l = threadIdx.x & 63;
  const int row = blockIdx.x * 4 + (threadIdx.x >> 6);

  const us8* hp = (const us8*)(h1 + (size_t)row * NH + l * 16);
  us8 hv0 = hp[0], hv1 = hp[1];
  float h[16];
#pragma unroll
  for (int j = 0; j < 8; ++j) { h[j] = bf2f(hv0[j]); h[8 + j] = bf2f(hv1[j]); }

  float y1[32];
#pragma unroll
  for (int j = 0; j < 32; ++j) {
    const us8* wp = (const us8*)(W1b + (size_t)j * NH + l * 16);
    us8 w0 = wp[0], w1 = wp[1];
    float d = 0.f;
#pragma unroll
    for (int k = 0; k < 8; ++k) {
      d = fmaf(h[k], bf2f(w0[k]), d);
      d = fmaf(h[8 + k], bf2f(w1[k]), d);
    }
#pragma unroll
    for (int off2 = 32; off2 > 0; off2 >>= 1) d += __shfl_xor(d, off2);
    y1[j] = fmaxf(d + b1[j], 0.f);
  }

  float y2[16];
#pragma unroll
  for (int m = 0; m < 16; ++m) {
    float s = b2[m];
#pragma unroll
    for (int j = 0; j < 32; ++j) s = fmaf(W2[m * 32 + j], y1[j], s);
    y2[m] = fmaxf(s, 0.f);
  }
  float o0 = b3[0], o1 = b3[1];
#pragma unroll
  for (int k = 0; k < 16; ++k) {
    o0 = fmaf(W3[k], y2[k], o0);
    o1 = fmaf(W3[16 + k], y2[k], o1);
  }
  float n0 = cin[row * 2] + o0;
  float n1 = cin[row * 2 + 1] + o1;
  if (l == 0) {
    preds[row * 2] = n0; preds[row * 2 + 1] = n1;
    cout[row * 2] = n0;  cout[row * 2 + 1] = n1;
  }
#pragma unroll
  for (int q = 0; q < 4; ++q) {
    int e = l + q * 64;
    float v = fmaf(n0, Wemb[e * 2], fmaf(n1, Wemb[e * 2 + 1], bemb[e]));
    embout[(size_t)row * NE + e] = __float2bfloat16(fmaxf(v, 0.f));
  }
}

// ---------------- embedding of observed trajectory (all 8 steps) ----------------
__global__ void k_embed(const float* __restrict__ x, const float* __restrict__ W,
                        const float* __restrict__ b, bf16* __restrict__ out) {
  const int l = threadIdx.x & 63;
  const int row = (blockIdx.x * 256 + threadIdx.x) >> 6;
  float x0 = x[row * 2], x1 = x[row * 2 + 1];
#pragma unroll
  for (int q = 0; q < 4; ++q) {
    int e = l + q * 64;
    float v = fmaf(x0, W[e * 2], fmaf(x1, W[e * 2 + 1], b[e]));
    out[(size_t)row * NE + e] = __float2bfloat16(fmaxf(v, 0.f));
  }
}

__global__ void k_f2b(const float* __restrict__ in, bf16* __restrict__ out, int n) {
  int i = (blockIdx.x * 256 + threadIdx.x) * 4;
  if (i >= n) return;
  float4 v = *(const float4*)(in + i);
  out[i] = __float2bfloat16(v.x);
  out[i + 1] = __float2bfloat16(v.y);
  out[i + 2] = __float2bfloat16(v.z);
  out[i + 3] = __float2bfloat16(v.w);
}

__global__ void k_badd(const float* __restrict__ a, const float* __restrict__ b,
                       float* __restrict__ o, int n) {
  int i = blockIdx.x * 256 + threadIdx.x;
  if (i < n) o[i] = a[i] + b[i];
}

extern "C" void kernel_launch(void* const* d_in, const int* in_sizes, int n_in,
                              void* d_out, int out_size, void* d_ws, size_t ws_size,
                              hipStream_t stream) {
  const float* obs   = (const float*)d_in[0];
  const float* Wemb  = (const float*)d_in[1];
  const float* bemb  = (const float*)d_in[2];
  const float* Wih0f = (const float*)d_in[3];
  const float* Whh0f = (const float*)d_in[4];
  const float* bih0  = (const float*)d_in[5];
  const float* bhh0  = (const float*)d_in[6];
  const float* Wih1f = (const float*)d_in[7];
  const float* Whh1f = (const float*)d_in[8];
  const float* bih1  = (const float*)d_in[9];
  const float* bhh1  = (const float*)d_in[10];
  const float* W1f   = (const float*)d_in[11];
  const float* b1m   = (const float*)d_in[12];
  const float* W2    = (const float*)d_in[13];
  const float* b2    = (const float*)d_in[14];
  const float* W3    = (const float*)d_in[15];
  const float* b3    = (const float*)d_in[16];

  char* ws = (char*)d_ws;
  size_t off = 0;
  auto alloc = [&](size_t bytes) -> void* {
    void* p = ws + off;
    off += (bytes + 255) & ~(size_t)255;
    return p;
  };
  bf16* wih0 = (bf16*)alloc((size_t)4096 * 256 * 2);
  bf16* whh0 = (bf16*)alloc((size_t)4096 * 1024 * 2);
  bf16* wih1 = (bf16*)alloc((size_t)4096 * 1024 * 2);
  bf16* whh1 = (bf16*)alloc((size_t)4096 * 1024 * 2);
  bf16* w1b  = (bf16*)alloc((size_t)32 * 1024 * 2);
  float* b0c = (float*)alloc((size_t)4096 * 4);
  float* b1c = (float*)alloc((size_t)4096 * 4);
  bf16* emb  = (bf16*)alloc((size_t)8 * NB * NE * 2);
  bf16* h0a  = (bf16*)alloc((size_t)NB * NH * 2);
  bf16* h0b  = (bf16*)alloc((size_t)NB * NH * 2);
  bf16* h1a  = (bf16*)alloc((size_t)NB * NH * 2);
  bf16* h1b  = (bf16*)alloc((size_t)NB * NH * 2);
  float* c0  = (float*)alloc((size_t)NB * NH * 4);
  float* c1  = (float*)alloc((size_t)NB * NH * 4);
  float* curr = (float*)alloc((size_t)NB * 2 * 4);
  bf16* cemb = (bf16*)alloc((size_t)NB * NE * 2);

  // weight conversion fp32 -> bf16, bias combine
  k_f2b<<<1024, 256, 0, stream>>>(Wih0f, wih0, 4096 * 256);
  k_f2b<<<4096, 256, 0, stream>>>(Whh0f, whh0, 4096 * 1024);
  k_f2b<<<4096, 256, 0, stream>>>(Wih1f, wih1, 4096 * 1024);
  k_f2b<<<4096, 256, 0, stream>>>(Whh1f, whh1, 4096 * 1024);
  k_f2b<<<32, 256, 0, stream>>>(W1f, w1b, 32 * 1024);
  k_badd<<<16, 256, 0, stream>>>(bih0, bhh0, b0c, 4096);
  k_badd<<<16, 256, 0, stream>>>(bih1, bhh1, b1c, 4096);
  k_embed<<<(8 * NB) / 4, 256, 0, stream>>>(obs, Wemb, bemb, emb);

  bf16* h0buf[2] = {h0a, h0b};
  bf16* h1buf[2] = {h1a, h1b};
  float* preds = (float*)d_out;

  for (int t = 0; t < 20; ++t) {
    const bf16* xin;
    if (t < 8)       xin = emb + (size_t)t * NB * NE;
    else if (t == 8) xin = emb + (size_t)7 * NB * NE;  // curr_emb(0) == embed(obs[-1])
    else             xin = cemb;
    int cu = t & 1, pv = cu ^ 1;
    int kh = (t == 0) ? 0 : NH;  // h,c start at zero: skip recurrent K and c read at t=0
    k_cell<<<2048, 256, 0, stream>>>(xin, NE, NE, h0buf[pv], kh,
                                     wih0, whh0, b0c, c0, h0buf[cu], t == 0);
    k_cell<<<2048, 256, 0, stream>>>(h0buf[cu], NH, NH, h1buf[pv], kh,
                                     wih1, whh1, b1c, c1, h1buf[cu], t == 0);
    if (t >= 8) {
      int p = t - 8;
      const float* cin = (p == 0) ? (obs + (size_t)7 * NB * 2) : curr;
      k_mlp<<<NB / 4, 256, 0, stream>>>(h1buf[cu], w1b, b1m, W2, b2, W3, b3,
                                        cin, curr, preds + (size_t)p * NB * 2,
                                        Wemb, bemb, cemb);
    }
  }
}

// Round 2
// 5670.517 us; speedup vs baseline: 1.0898x; 1.0898x over previous
//
#include <hip/hip_runtime.h>
#include <hip/hip_bf16.h>
#include <stdint.h>

typedef __hip_bfloat16 bf16;
typedef __attribute__((ext_vector_type(8))) short bf16x8;
typedef __attribute__((ext_vector_type(4))) float f32x4;
typedef __attribute__((ext_vector_type(8))) unsigned short us8;

#define NB 8192
#define NE 256
#define NH 1024

__device__ __forceinline__ float bf2f(unsigned short u) {
  union { unsigned int i; float f; } x; x.i = ((unsigned int)u) << 16; return x.f;
}
__device__ __forceinline__ float sigm(float x) {
  return __builtin_amdgcn_rcpf(1.f + __expf(-x));
}
__device__ __forceinline__ float tanh_f(float x) {
  return 1.f - 2.f * __builtin_amdgcn_rcpf(1.f + __expf(2.f * x));
}

#define BAR() __builtin_amdgcn_s_barrier()
#define LGKM0() do { asm volatile("s_waitcnt lgkmcnt(0)" ::: "memory"); \
                     __builtin_amdgcn_sched_barrier(0); } while (0)
#define VMW(N) asm volatile("s_waitcnt vmcnt(" #N ")" ::: "memory")

// 16 MFMA cluster: one m-half (4 m-frags) x 4 gates, setprio-wrapped (T5)
#define MFMA16(MH, AF, BV)                                                    \
  do {                                                                        \
    __builtin_amdgcn_s_setprio(1);                                            \
    _Pragma("unroll") for (int i_ = 0; i_ < 4; ++i_)                          \
      _Pragma("unroll") for (int g_ = 0; g_ < 4; ++g_)                        \
        acc[(MH)*4 + i_][g_] = __builtin_amdgcn_mfma_f32_16x16x32_bf16(       \
            AF[i_], BV[g_], acc[(MH)*4 + i_][g_], 0, 0, 0);                   \
    __builtin_amdgcn_s_setprio(0);                                            \
  } while (0)

// ds_read A-frags: 4 m-frags of m-half MH, k-slice KK (XOR-swizzled chunk)
#define LDA(BUF, MH, KK, AF)                                                  \
  do {                                                                        \
    const char* Ab_ = (const char*)&As[BUF][0][0];                            \
    _Pragma("unroll") for (int i_ = 0; i_ < 4; ++i_)                          \
      AF[i_] = *(const bf16x8*)(Ab_ +                                         \
          (wr * 128 + (MH)*64 + i_ * 16 + l15) * 128 + co##KK);               \
  } while (0)

// ds_read B-frags: 4 gates, k-slice KK
#define LDB(BUF, KK, BV)                                                      \
  do {                                                                        \
    const char* Bb_ = (const char*)&Bs[BUF][0][0];                            \
    _Pragma("unroll") for (int g_ = 0; g_ < 4; ++g_)                          \
      BV[g_] = *(const bf16x8*)(Bb_ + (g_ * 64 + nc * 16 + l15) * 128 + co##KK); \
  } while (0)

// ---------------- fused GEMM + LSTM cell, 256x256 8-phase ----------------
// gates = X@Wih^T + Hin@Whh^T + bias ; c' = sig(f)*c + sig(i)*tanh(g); h = sig(o)*tanh(c')
// Block: 256 M-rows x (64 hcols x 4 gates). 8 waves (2M x 4N), wave = 128x64.
// Wave n-frags = the 4 gates -> epilogue fully in-register.
__global__ __launch_bounds__(512) void k_cell(
    const bf16* __restrict__ X, int ldx, int Kx,
    const bf16* __restrict__ Hin, int Kh,
    const bf16* __restrict__ Wih, const bf16* __restrict__ Whh,
    const float* __restrict__ bias, float* __restrict__ Cst,
    bf16* __restrict__ Hout, int czero)
{
  __shared__ bf16 As[2][256][64];
  __shared__ bf16 Bs[2][256][64];

  const int tid = threadIdx.x;
  const int l = tid & 63;
  const int l15 = l & 15;
  const int wv = tid >> 6;          // wave 0..7
  const int wr = wv >> 2;           // M-half of block (0..1)
  const int nc = wv & 3;            // N-wave (16 hcols each)

  // XCD-bijective swizzle: 512 blocks, 64 per XCD; 32 concurrent blocks per
  // XCD share one weight n-panel (L2-resident).
  const int bid = blockIdx.x;
  const int swz = (bid & 7) * 64 + (bid >> 3);
  const int m0 = (swz & 31) * 256;
  const int hc0 = (swz >> 5) * 64;

  const int NT = (Kx + Kh) >> 6;
  const int T = NT >> 1;

  // staging constants: per-issue thread -> (row = tid>>3, chunk swizzled)
  const int rowid = tid >> 3;
  const int ch = (tid & 7) ^ (rowid & 7);
  const int wv8 = wv * 8;

  // read-side swizzled chunk byte offsets for kk=0,1
  const int co0 = (((l >> 4) + 0) ^ (l & 7)) * 16;
  const int co1 = (((l >> 4) + 4) ^ (l & 7)) * 16;

  f32x4 acc[8][4];
  f32x4 zero4 = {0.f, 0.f, 0.f, 0.f};
#pragma unroll
  for (int i = 0; i < 8; ++i)
#pragma unroll
    for (int j = 0; j < 4; ++j) acc[i][j] = zero4;

  // stage one 16KB half of A: rows {rnd*128 + half*64 .. +64) , K-tile kt
  auto stage_a = [&](int buf, int half, int kt) {
    int kc = kt << 6;
    const bf16* src; size_t ld;
    if (kc < Kx) { src = X + kc; ld = (size_t)ldx; }
    else         { src = Hin + (kc - Kx); ld = NH; }
#pragma unroll
    for (int rnd = 0; rnd < 2; ++rnd) {
      int tr = rnd * 128 + half * 64;
      const bf16* gp = src + (size_t)(m0 + tr + rowid) * ld + ch * 8;
      __builtin_amdgcn_global_load_lds(
          (const __attribute__((address_space(1))) void*)gp,
          (__attribute__((address_space(3))) void*)&As[buf][tr + wv8][0],
          16, 0, 0);
    }
  };
  // stage one 16KB half of B (gates rnd*2+half), K-tile kt
  auto stage_b = [&](int buf, int half, int kt) {
    int kc = kt << 6;
    const bf16* src; size_t ld;
    if (kc < Kx) { src = Wih + kc; ld = (size_t)Kx; }
    else         { src = Whh + (kc - Kx); ld = NH; }
#pragma unroll
    for (int rnd = 0; rnd < 2; ++rnd) {
      int gate = rnd * 2 + half;
      const bf16* gp = src + (size_t)(gate * NH + hc0 + rowid) * ld + ch * 8;
      __builtin_amdgcn_global_load_lds(
          (const __attribute__((address_space(1))) void*)gp,
          (__attribute__((address_space(3))) void*)&Bs[buf][gate * 64 + wv8][0],
          16, 0, 0);
    }
  };

  // prologue: buf0 = kt0 (all 4 halves, need-order first), + B1h0 of kt1
  stage_a(0, 0, 0);
  stage_b(0, 0, 0);
  stage_b(0, 1, 0);
  stage_a(0, 1, 0);
  stage_b(1, 0, 1);
  VMW(4);
  BAR();

  for (int t = 0; t < T; ++t) {
    const int kt1 = 2 * t + 1;
    const bool last = (t == T - 1);
    bf16x8 af[4], bv[4];

    // P1: compute buf0 (mh0,kk0); stage B1h1(kt1)
    LDB(0, 0, bv);
    LDA(0, 0, 0, af);
    stage_b(1, 1, kt1);
    BAR(); LGKM0();
    MFMA16(0, af, bv);
    VMW(4);            // guards P2's A0Hb (staged P7 prev iter / prologue)
    BAR();

    // P2: (mh1,kk0); stage A1Ha(kt1)
    LDA(0, 1, 0, af);
    stage_a(1, 0, kt1);
    BAR(); LGKM0();
    MFMA16(1, af, bv);
    BAR();

    // P3: (mh0,kk1); stage A1Hb(kt1)
    LDB(0, 1, bv);
    LDA(0, 0, 1, af);
    stage_a(1, 1, kt1);
    BAR(); LGKM0();
    MFMA16(0, af, bv);
    BAR();

    // P4: (mh1,kk1); stage A0Ha(kt0+2)
    LDA(0, 1, 1, af);
    if (!last) stage_a(0, 0, kt1 + 1);
    BAR(); LGKM0();
    MFMA16(1, af, bv);
    if (last) { VMW(2); } else { VMW(4); }  // guards P5: B1h0,B1h1,A1Ha
    BAR();

    // P5: compute buf1 (mh0,kk0); stage B0h0(kt0+2)
    LDB(1, 0, bv);
    LDA(1, 0, 0, af);
    if (!last) stage_b(0, 0, kt1 + 1);
    BAR(); LGKM0();
    MFMA16(0, af, bv);
    if (last) { VMW(0); } else { VMW(4); }  // guards P6: A1Hb
    BAR();

    // P6: (mh1,kk0); stage B0h1(kt0+2)
    LDA(1, 1, 0, af);
    if (!last) stage_b(0, 1, kt1 + 1);
    BAR(); LGKM0();
    MFMA16(1, af, bv);
    BAR();

    // P7: (mh0,kk1); stage A0Hb(kt0+2)
    LDB(1, 1, bv);
    LDA(1, 0, 1, af);
    if (!last) stage_a(0, 1, kt1 + 1);
    BAR(); LGKM0();
    MFMA16(0, af, bv);
    BAR();

    // P8: (mh1,kk1); stage B1h0(kt0+3)
    LDA(1, 1, 1, af);
    if (kt1 + 2 < NT) stage_b(1, 0, kt1 + 2);
    BAR(); LGKM0();
    MFMA16(1, af, bv);
    if (!last) { VMW(4); }  // guards next P1: A0Ha,B0h0,B0h1
    BAR();
  }

  // epilogue: acc[m][gate][r]; C/D layout col=lane&15, row=(lane>>4)*4+r
  const int ecol = hc0 + nc * 16 + l15;
  const float bi = bias[ecol];
  const float bff = bias[NH + ecol];
  const float bg = bias[2 * NH + ecol];
  const float bo = bias[3 * NH + ecol];
  const int r0 = m0 + wr * 128 + ((l >> 4) << 2);
#pragma unroll
  for (int m = 0; m < 8; ++m) {
#pragma unroll
    for (int r = 0; r < 4; ++r) {
      int row = r0 + m * 16 + r;
      size_t idx = (size_t)row * NH + ecol;
      float gi = sigm(acc[m][0][r] + bi);
      float gf = sigm(acc[m][1][r] + bff);
      float gg = tanh_f(acc[m][2][r] + bg);
      float go = sigm(acc[m][3][r] + bo);
      float cold = czero ? 0.f : Cst[idx];
      float cn = gf * cold + gi * gg;
      Cst[idx] = cn;
      Hout[idx] = __float2bfloat16(go * tanh_f(cn));
    }
  }
}

// ---------------- MLP decode head + displacement add + re-embed ----------------
__global__ __launch_bounds__(256) void k_mlp(
    const bf16* __restrict__ h1, const bf16* __restrict__ W1b, const float* __restrict__ b1,
    const float* __restrict__ W2, const float* __restrict__ b2,
    const float* __restrict__ W3, const float* __restrict__ b3,
    const float* __restrict__ cin, float* __restrict__ cout,
    float* __restrict__ preds, const float* __restrict__ Wemb,
    const float* __restrict__ bemb, bf16* __restrict__ embout)
{
  const int l = threadIdx.x & 63;
  const int row = blockIdx.x * 4 + (threadIdx.x >> 6);

  const us8* hp = (const us8*)(h1 + (size_t)row * NH + l * 16);
  us8 hv0 = hp[0], hv1 = hp[1];
  float h[16];
#pragma unroll
  for (int j = 0; j < 8; ++j) { h[j] = bf2f(hv0[j]); h[8 + j] = bf2f(hv1[j]); }

  float y1[32];
#pragma unroll
  for (int j = 0; j < 32; ++j) {
    const us8* wp = (const us8*)(W1b + (size_t)j * NH + l * 16);
    us8 w0 = wp[0], w1 = wp[1];
    float d = 0.f;
#pragma unroll
    for (int k = 0; k < 8; ++k) {
      d = fmaf(h[k], bf2f(w0[k]), d);
      d = fmaf(h[8 + k], bf2f(w1[k]), d);
    }
#pragma unroll
    for (int off2 = 32; off2 > 0; off2 >>= 1) d += __shfl_xor(d, off2);
    y1[j] = fmaxf(d + b1[j], 0.f);
  }

  float y2[16];
#pragma unroll
  for (int m = 0; m < 16; ++m) {
    float s = b2[m];
#pragma unroll
    for (int j = 0; j < 32; ++j) s = fmaf(W2[m * 32 + j], y1[j], s);
    y2[m] = fmaxf(s, 0.f);
  }
  float o0 = b3[0], o1 = b3[1];
#pragma unroll
  for (int k = 0; k < 16; ++k) {
    o0 = fmaf(W3[k], y2[k], o0);
    o1 = fmaf(W3[16 + k], y2[k], o1);
  }
  float n0 = cin[row * 2] + o0;
  float n1 = cin[row * 2 + 1] + o1;
  if (l == 0) {
    preds[row * 2] = n0; preds[row * 2 + 1] = n1;
    cout[row * 2] = n0;  cout[row * 2 + 1] = n1;
  }
#pragma unroll
  for (int q = 0; q < 4; ++q) {
    int e = l + q * 64;
    float v = fmaf(n0, Wemb[e * 2], fmaf(n1, Wemb[e * 2 + 1], bemb[e]));
    embout[(size_t)row * NE + e] = __float2bfloat16(fmaxf(v, 0.f));
  }
}

// ---------------- embedding of observed trajectory (all 8 steps) ----------------
__global__ void k_embed(const float* __restrict__ x, const float* __restrict__ W,
                        const float* __restrict__ b, bf16* __restrict__ out) {
  const int l = threadIdx.x & 63;
  const int row = (blockIdx.x * 256 + threadIdx.x) >> 6;
  float x0 = x[row * 2], x1 = x[row * 2 + 1];
#pragma unroll
  for (int q = 0; q < 4; ++q) {
    int e = l + q * 64;
    float v = fmaf(x0, W[e * 2], fmaf(x1, W[e * 2 + 1], b[e]));
    out[(size_t)row * NE + e] = __float2bfloat16(fmaxf(v, 0.f));
  }
}

__global__ void k_f2b(const float* __restrict__ in, bf16* __restrict__ out, int n) {
  int i = (blockIdx.x * 256 + threadIdx.x) * 4;
  if (i >= n) return;
  float4 v = *(const float4*)(in + i);
  out[i] = __float2bfloat16(v.x);
  out[i + 1] = __float2bfloat16(v.y);
  out[i + 2] = __float2bfloat16(v.z);
  out[i + 3] = __float2bfloat16(v.w);
}

__global__ void k_badd(const float* __restrict__ a, const float* __restrict__ b,
                       float* __restrict__ o, int n) {
  int i = blockIdx.x * 256 + threadIdx.x;
  if (i < n) o[i] = a[i] + b[i];
}

extern "C" void kernel_launch(void* const* d_in, const int* in_sizes, int n_in,
                              void* d_out, int out_size, void* d_ws, size_t ws_size,
                              hipStream_t stream) {
  const float* obs   = (const float*)d_in[0];
  const float* Wemb  = (const float*)d_in[1];
  const float* bemb  = (const float*)d_in[2];
  const float* Wih0f = (const float*)d_in[3];
  const float* Whh0f = (const float*)d_in[4];
  const float* bih0  = (const float*)d_in[5];
  const float* bhh0  = (const float*)d_in[6];
  const float* Wih1f = (const float*)d_in[7];
  const float* Whh1f = (const float*)d_in[8];
  const float* bih1  = (const float*)d_in[9];
  const float* bhh1  = (const float*)d_in[10];
  const float* W1f   = (const float*)d_in[11];
  const float* b1m   = (const float*)d_in[12];
  const float* W2    = (const float*)d_in[13];
  const float* b2    = (const float*)d_in[14];
  const float* W3    = (const float*)d_in[15];
  const float* b3    = (const float*)d_in[16];

  char* ws = (char*)d_ws;
  size_t off = 0;
  auto alloc = [&](size_t bytes) -> void* {
    void* p = ws + off;
    off += (bytes + 255) & ~(size_t)255;
    return p;
  };
  bf16* wih0 = (bf16*)alloc((size_t)4096 * 256 * 2);
  bf16* whh0 = (bf16*)alloc((size_t)4096 * 1024 * 2);
  bf16* wih1 = (bf16*)alloc((size_t)4096 * 1024 * 2);
  bf16* whh1 = (bf16*)alloc((size_t)4096 * 1024 * 2);
  bf16* w1b  = (bf16*)alloc((size_t)32 * 1024 * 2);
  float* b0c = (float*)alloc((size_t)4096 * 4);
  float* b1c = (float*)alloc((size_t)4096 * 4);
  bf16* emb  = (bf16*)alloc((size_t)8 * NB * NE * 2);
  bf16* h0a  = (bf16*)alloc((size_t)NB * NH * 2);
  bf16* h0b  = (bf16*)alloc((size_t)NB * NH * 2);
  bf16* h1a  = (bf16*)alloc((size_t)NB * NH * 2);
  bf16* h1b  = (bf16*)alloc((size_t)NB * NH * 2);
  float* c0  = (float*)alloc((size_t)NB * NH * 4);
  float* c1  = (float*)alloc((size_t)NB * NH * 4);
  float* curr = (float*)alloc((size_t)NB * 2 * 4);
  bf16* cemb = (bf16*)alloc((size_t)NB * NE * 2);

  // weight conversion fp32 -> bf16, bias combine
  k_f2b<<<1024, 256, 0, stream>>>(Wih0f, wih0, 4096 * 256);
  k_f2b<<<4096, 256, 0, stream>>>(Whh0f, whh0, 4096 * 1024);
  k_f2b<<<4096, 256, 0, stream>>>(Wih1f, wih1, 4096 * 1024);
  k_f2b<<<4096, 256, 0, stream>>>(Whh1f, whh1, 4096 * 1024);
  k_f2b<<<32, 256, 0, stream>>>(W1f, w1b, 32 * 1024);
  k_badd<<<16, 256, 0, stream>>>(bih0, bhh0, b0c, 4096);
  k_badd<<<16, 256, 0, stream>>>(bih1, bhh1, b1c, 4096);
  k_embed<<<(8 * NB) / 4, 256, 0, stream>>>(obs, Wemb, bemb, emb);

  bf16* h0buf[2] = {h0a, h0b};
  bf16* h1buf[2] = {h1a, h1b};
  float* preds = (float*)d_out;

  for (int t = 0; t < 20; ++t) {
    const bf16* xin;
    if (t < 8)       xin = emb + (size_t)t * NB * NE;
    else if (t == 8) xin = emb + (size_t)7 * NB * NE;  // curr_emb(0) == embed(obs[-1])
    else             xin = cemb;
    int cu = t & 1, pv = cu ^ 1;
    int kh = (t == 0) ? 0 : NH;  // h,c start at zero: skip recurrent K and c read at t=0
    k_cell<<<512, 512, 0, stream>>>(xin, NE, NE, h0buf[pv], kh,
                                    wih0, whh0, b0c, c0, h0buf[cu], t == 0);
    k_cell<<<512, 512, 0, stream>>>(h0buf[cu], NH, NH, h1buf[pv], kh,
                                    wih1, whh1, b1c, c1, h1buf[cu], t == 0);
    if (t >= 8) {
      int p = t - 8;
      const float* cin = (p == 0) ? (obs + (size_t)7 * NB * 2) : curr;
      k_mlp<<<NB / 4, 256, 0, stream>>>(h1buf[cu], w1b, b1m, W2, b2, W3, b3,
                                        cin, curr, preds + (size_t)p * NB * 2,
                                        Wemb, bemb, cemb);
    }
  }
}

// Round 3
// 5000.774 us; speedup vs baseline: 1.2357x; 1.1339x over previous
//
#include <hip/hip_runtime.h>
#include <hip/hip_bf16.h>
#include <stdint.h>

typedef __hip_bfloat16 bf16;
typedef __attribute__((ext_vector_type(8))) short bf16x8;
typedef __attribute__((ext_vector_type(4))) float f32x4;
typedef __attribute__((ext_vector_type(8))) unsigned short us8;

#define NB 8192
#define NE 256
#define NH 1024

__device__ __forceinline__ float bf2f(unsigned short u) {
  union { unsigned int i; float f; } x; x.i = ((unsigned int)u) << 16; return x.f;
}
__device__ __forceinline__ float sigm(float x) {
  return __builtin_amdgcn_rcpf(1.f + __expf(-x));
}
__device__ __forceinline__ float tanh_f(float x) {
  return 1.f - 2.f * __builtin_amdgcn_rcpf(1.f + __expf(2.f * x));
}

#define BAR() __builtin_amdgcn_s_barrier()
#define LGKM0() do { asm volatile("s_waitcnt lgkmcnt(0)" ::: "memory"); \
                     __builtin_amdgcn_sched_barrier(0); } while (0)
#define VMW(N) asm volatile("s_waitcnt vmcnt(" #N ")" ::: "memory")

// 32-MFMA cluster: one m-half (4 m-frags) x 4 gates x 2 k-slices (T5 setprio)
#define MFMA32(MH)                                                            \
  do {                                                                        \
    __builtin_amdgcn_s_setprio(1);                                            \
    _Pragma("unroll") for (int i_ = 0; i_ < 4; ++i_)                          \
      _Pragma("unroll") for (int g_ = 0; g_ < 4; ++g_) {                      \
        acc[(MH)*4 + i_][g_] = __builtin_amdgcn_mfma_f32_16x16x32_bf16(       \
            af[i_], bv[g_], acc[(MH)*4 + i_][g_], 0, 0, 0);                   \
        acc[(MH)*4 + i_][g_] = __builtin_amdgcn_mfma_f32_16x16x32_bf16(       \
            af[4 + i_], bv[4 + g_], acc[(MH)*4 + i_][g_], 0, 0, 0);           \
      }                                                                       \
    __builtin_amdgcn_s_setprio(0);                                            \
  } while (0)

// ds_read A-frags: 4 m-frags of m-half MH, both k-slices (XOR-swizzled)
#define LDA8(BUF, MH)                                                         \
  do {                                                                        \
    const char* Ab_ = (const char*)&As[BUF][0][0];                            \
    _Pragma("unroll") for (int i_ = 0; i_ < 4; ++i_) {                        \
      int ro_ = (wr * 128 + (MH)*64 + i_ * 16 + l15) * 128;                   \
      af[i_]     = *(const bf16x8*)(Ab_ + ro_ + co0);                         \
      af[4 + i_] = *(const bf16x8*)(Ab_ + ro_ + co1);                         \
    }                                                                         \
  } while (0)

// ds_read B-frags: 4 gates, both k-slices
#define LDB8(BUF)                                                             \
  do {                                                                        \
    const char* Bb_ = (const char*)&Bs[BUF][0][0];                            \
    _Pragma("unroll") for (int g_ = 0; g_ < 4; ++g_) {                        \
      int ro_ = (g_ * 64 + nc * 16 + l15) * 128;                              \
      bv[g_]     = *(const bf16x8*)(Bb_ + ro_ + co0);                         \
      bv[4 + g_] = *(const bf16x8*)(Bb_ + ro_ + co1);                         \
    }                                                                         \
  } while (0)

// ---------------- fused GEMM + LSTM cell, 256x256, 4-phase/iter ----------------
// gates = X@Wih^T + Hin@Whh^T + bias ; c' = sig(f)*c + sig(i)*tanh(g); h = sig(o)*tanh(c')
// Block: 256 M-rows x (64 hcols x 4 gates). 8 waves (2M x 4N), wave = 128x64.
// Wave n-frags = the 4 gates -> epilogue fully in-register.
__global__ __launch_bounds__(512, 2) void k_cell(
    const bf16* __restrict__ X, int ldx, int Kx,
    const bf16* __restrict__ Hin, int Kh,
    const bf16* __restrict__ Wih, const bf16* __restrict__ Whh,
    const float* __restrict__ bias, float* __restrict__ Cst,
    bf16* __restrict__ Hout, int czero)
{
  __shared__ bf16 As[2][256][64];
  __shared__ bf16 Bs[2][256][64];

  const int tid = threadIdx.x;
  const int l = tid & 63;
  const int l15 = l & 15;
  const int wv = tid >> 6;          // wave 0..7
  const int wr = wv >> 2;           // M-half of block (0..1)
  const int nc = wv & 3;            // N-wave (16 hcols each)

  // m-major XCD ownership: XCD x (= bid&7) owns m-tiles {4x..4x+3} x all hc.
  // Round-1 resident set per XCD: 4 A-panels (~4MB, L2-fit) x 8 W-panels (L3).
  const int bid = blockIdx.x;
  const int xcd = bid & 7, j = bid >> 3;
  const int m0 = (xcd * 4 + (j & 3)) * 256;
  const int hc0 = (j >> 2) * 64;

  const int NT = (Kx + Kh) >> 6;
  const int T = NT >> 1;

  // staging: thread -> (row = tid>>3, chunk XOR-swizzled vs row)
  const int rowid = tid >> 3;
  const int ch = (tid & 7) ^ (rowid & 7);
  const int wv8 = wv * 8;

  // read-side swizzled chunk byte offsets for k-slices 0,1
  const int co0 = (((l >> 4) + 0) ^ (l & 7)) * 16;
  const int co1 = (((l >> 4) + 4) ^ (l & 7)) * 16;

  f32x4 acc[8][4];
  f32x4 zero4 = {0.f, 0.f, 0.f, 0.f};
#pragma unroll
  for (int i = 0; i < 8; ++i)
#pragma unroll
    for (int j2 = 0; j2 < 4; ++j2) acc[i][j2] = zero4;

  // A halves: half0 = rows {0-63,128-191} (mh0 for both wr), half1 = {64-127,192-255}
  auto stage_a = [&](int buf, int half, int kt) {
    int kc = kt << 6;
    const bf16* src; size_t ld;
    if (kc < Kx) { src = X + kc; ld = (size_t)ldx; }
    else         { src = Hin + (kc - Kx); ld = NH; }
#pragma unroll
    for (int rnd = 0; rnd < 2; ++rnd) {
      int tr = rnd * 128 + half * 64;
      const bf16* gp = src + (size_t)(m0 + tr + rowid) * ld + ch * 8;
      __builtin_amdgcn_global_load_lds(
          (const __attribute__((address_space(1))) void*)gp,
          (__attribute__((address_space(3))) void*)&As[buf][tr + wv8][0],
          16, 0, 0);
    }
  };
  // B halves: half0 = gates {0,2}, half1 = gates {1,3}
  auto stage_b = [&](int buf, int half, int kt) {
    int kc = kt << 6;
    const bf16* src; size_t ld;
    if (kc < Kx) { src = Wih + kc; ld = (size_t)Kx; }
    else         { src = Whh + (kc - Kx); ld = NH; }
#pragma unroll
    for (int rnd = 0; rnd < 2; ++rnd) {
      int gate = rnd * 2 + half;
      const bf16* gp = src + (size_t)(gate * NH + hc0 + rowid) * ld + ch * 8;
      __builtin_amdgcn_global_load_lds(
          (const __attribute__((address_space(1))) void*)gp,
          (__attribute__((address_space(3))) void*)&Bs[buf][gate * 64 + wv8][0],
          16, 0, 0);
    }
  };

  // prologue: full b0(kt0) + A1.h0(kt1)  -> enters loop in steady state
  stage_a(0, 0, 0);
  stage_a(0, 1, 0);
  stage_b(0, 0, 0);
  stage_b(0, 1, 0);
  stage_a(1, 0, 1);
  VMW(2);   // b0 complete; A1.h0 in flight
  BAR();

  for (int t = 0; t < T; ++t) {
    const int kt1 = 2 * t + 1;
    const bool last = (t == T - 1);
    bf16x8 af[8], bv[8];

    // Ph1: compute b0.mh0 ; stage A1.h1 + B1 (kt1)
    LDB8(0); LDA8(0, 0);
    stage_a(1, 1, kt1);
    stage_b(1, 0, kt1);
    stage_b(1, 1, kt1);
    BAR(); LGKM0();
    MFMA32(0);
    BAR();

    // Ph2: compute b0.mh1 ; stage A0.h0 (kt0+2)
    LDA8(0, 1);
    if (!last) stage_a(0, 0, kt1 + 1);
    BAR(); LGKM0();
    MFMA32(1);
    if (last) { VMW(0); } else { VMW(2); }  // complete b1(kt1); leave A0.h0
    BAR();

    // Ph3: compute b1.mh0 ; stage A0.h1 + B0 (kt0+2)
    LDB8(1); LDA8(1, 0);
    if (!last) {
      stage_a(0, 1, kt1 + 1);
      stage_b(0, 0, kt1 + 1);
      stage_b(0, 1, kt1 + 1);
    }
    BAR(); LGKM0();
    MFMA32(0);
    BAR();

    // Ph4: compute b1.mh1 ; stage A1.h0 (kt1+2)
    LDA8(1, 1);
    if (!last) stage_a(1, 0, kt1 + 2);
    BAR(); LGKM0();
    MFMA32(1);
    if (!last) { VMW(2); }  // complete b0(kt0+2); leave A1.h0(kt1+2)
    BAR();
  }

  // epilogue: acc[m][gate][r]; C/D layout col=lane&15, row=(lane>>4)*4+r
  const int ecol = hc0 + nc * 16 + l15;
  const float bi = bias[ecol];
  const float bff = bias[NH + ecol];
  const float bg = bias[2 * NH + ecol];
  const float bo = bias[3 * NH + ecol];
  const int r0 = m0 + wr * 128 + ((l >> 4) << 2);
#pragma unroll
  for (int m = 0; m < 8; ++m) {
#pragma unroll
    for (int r = 0; r < 4; ++r) {
      int row = r0 + m * 16 + r;
      size_t idx = (size_t)row * NH + ecol;
      float gi = sigm(acc[m][0][r] + bi);
      float gf = sigm(acc[m][1][r] + bff);
      float gg = tanh_f(acc[m][2][r] + bg);
      float go = sigm(acc[m][3][r] + bo);
      float cold = czero ? 0.f : Cst[idx];
      float cn = gf * cold + gi * gg;
      Cst[idx] = cn;
      Hout[idx] = __float2bfloat16(go * tanh_f(cn));
    }
  }
}

// ---------------- MLP decode head + displacement add + re-embed ----------------
__global__ __launch_bounds__(256) void k_mlp(
    const bf16* __restrict__ h1, const bf16* __restrict__ W1b, const float* __restrict__ b1,
    const float* __restrict__ W2, const float* __restrict__ b2,
    const float* __restrict__ W3, const float* __restrict__ b3,
    const float* __restrict__ cin, float* __restrict__ cout,
    float* __restrict__ preds, const float* __restrict__ Wemb,
    const float* __restrict__ bemb, bf16* __restrict__ embout)
{
  const int l = threadIdx.x & 63;
  const int row = blockIdx.x * 4 + (threadIdx.x >> 6);

  const us8* hp = (const us8*)(h1 + (size_t)row * NH + l * 16);
  us8 hv0 = hp[0], hv1 = hp[1];
  float h[16];
#pragma unroll
  for (int j = 0; j < 8; ++j) { h[j] = bf2f(hv0[j]); h[8 + j] = bf2f(hv1[j]); }

  float y1[32];
#pragma unroll
  for (int j = 0; j < 32; ++j) {
    const us8* wp = (const us8*)(W1b + (size_t)j * NH + l * 16);
    us8 w0 = wp[0], w1 = wp[1];
    float d = 0.f;
#pragma unroll
    for (int k = 0; k < 8; ++k) {
      d = fmaf(h[k], bf2f(w0[k]), d);
      d = fmaf(h[8 + k], bf2f(w1[k]), d);
    }
#pragma unroll
    for (int off2 = 32; off2 > 0; off2 >>= 1) d += __shfl_xor(d, off2);
    y1[j] = fmaxf(d + b1[j], 0.f);
  }

  float y2[16];
#pragma unroll
  for (int m = 0; m < 16; ++m) {
    float s = b2[m];
#pragma unroll
    for (int j = 0; j < 32; ++j) s = fmaf(W2[m * 32 + j], y1[j], s);
    y2[m] = fmaxf(s, 0.f);
  }
  float o0 = b3[0], o1 = b3[1];
#pragma unroll
  for (int k = 0; k < 16; ++k) {
    o0 = fmaf(W3[k], y2[k], o0);
    o1 = fmaf(W3[16 + k], y2[k], o1);
  }
  float n0 = cin[row * 2] + o0;
  float n1 = cin[row * 2 + 1] + o1;
  if (l == 0) {
    preds[row * 2] = n0; preds[row * 2 + 1] = n1;
    cout[row * 2] = n0;  cout[row * 2 + 1] = n1;
  }
#pragma unroll
  for (int q = 0; q < 4; ++q) {
    int e = l + q * 64;
    float v = fmaf(n0, Wemb[e * 2], fmaf(n1, Wemb[e * 2 + 1], bemb[e]));
    embout[(size_t)row * NE + e] = __float2bfloat16(fmaxf(v, 0.f));
  }
}

// ---------------- embedding of observed trajectory (all 8 steps) ----------------
__global__ void k_embed(const float* __restrict__ x, const float* __restrict__ W,
                        const float* __restrict__ b, bf16* __restrict__ out) {
  const int l = threadIdx.x & 63;
  const int row = (blockIdx.x * 256 + threadIdx.x) >> 6;
  float x0 = x[row * 2], x1 = x[row * 2 + 1];
#pragma unroll
  for (int q = 0; q < 4; ++q) {
    int e = l + q * 64;
    float v = fmaf(x0, W[e * 2], fmaf(x1, W[e * 2 + 1], b[e]));
    out[(size_t)row * NE + e] = __float2bfloat16(fmaxf(v, 0.f));
  }
}

__global__ void k_f2b(const float* __restrict__ in, bf16* __restrict__ out, int n) {
  int i = (blockIdx.x * 256 + threadIdx.x) * 4;
  if (i >= n) return;
  float4 v = *(const float4*)(in + i);
  out[i] = __float2bfloat16(v.x);
  out[i + 1] = __float2bfloat16(v.y);
  out[i + 2] = __float2bfloat16(v.z);
  out[i + 3] = __float2bfloat16(v.w);
}

__global__ void k_badd(const float* __restrict__ a, const float* __restrict__ b,
                       float* __restrict__ o, int n) {
  int i = blockIdx.x * 256 + threadIdx.x;
  if (i < n) o[i] = a[i] + b[i];
}

extern "C" void kernel_launch(void* const* d_in, const int* in_sizes, int n_in,
                              void* d_out, int out_size, void* d_ws, size_t ws_size,
                              hipStream_t stream) {
  const float* obs   = (const float*)d_in[0];
  const float* Wemb  = (const float*)d_in[1];
  const float* bemb  = (const float*)d_in[2];
  const float* Wih0f = (const float*)d_in[3];
  const float* Whh0f = (const float*)d_in[4];
  const float* bih0  = (const float*)d_in[5];
  const float* bhh0  = (const float*)d_in[6];
  const float* Wih1f = (const float*)d_in[7];
  const float* Whh1f = (const float*)d_in[8];
  const float* bih1  = (const float*)d_in[9];
  const float* bhh1  = (const float*)d_in[10];
  const float* W1f   = (const float*)d_in[11];
  const float* b1m   = (const float*)d_in[12];
  const float* W2    = (const float*)d_in[13];
  const float* b2    = (const float*)d_in[14];
  const float* W3    = (const float*)d_in[15];
  const float* b3    = (const float*)d_in[16];

  char* ws = (char*)d_ws;
  size_t off = 0;
  auto alloc = [&](size_t bytes) -> void* {
    void* p = ws + off;
    off += (bytes + 255) & ~(size_t)255;
    return p;
  };
  bf16* wih0 = (bf16*)alloc((size_t)4096 * 256 * 2);
  bf16* whh0 = (bf16*)alloc((size_t)4096 * 1024 * 2);
  bf16* wih1 = (bf16*)alloc((size_t)4096 * 1024 * 2);
  bf16* whh1 = (bf16*)alloc((size_t)4096 * 1024 * 2);
  bf16* w1b  = (bf16*)alloc((size_t)32 * 1024 * 2);
  float* b0c = (float*)alloc((size_t)4096 * 4);
  float* b1c = (float*)alloc((size_t)4096 * 4);
  bf16* emb  = (bf16*)alloc((size_t)8 * NB * NE * 2);
  bf16* h0a  = (bf16*)alloc((size_t)NB * NH * 2);
  bf16* h0b  = (bf16*)alloc((size_t)NB * NH * 2);
  bf16* h1a  = (bf16*)alloc((size_t)NB * NH * 2);
  bf16* h1b  = (bf16*)alloc((size_t)NB * NH * 2);
  float* c0  = (float*)alloc((size_t)NB * NH * 4);
  float* c1  = (float*)alloc((size_t)NB * NH * 4);
  float* curr = (float*)alloc((size_t)NB * 2 * 4);
  bf16* cemb = (bf16*)alloc((size_t)NB * NE * 2);

  // weight conversion fp32 -> bf16, bias combine
  k_f2b<<<1024, 256, 0, stream>>>(Wih0f, wih0, 4096 * 256);
  k_f2b<<<4096, 256, 0, stream>>>(Whh0f, whh0, 4096 * 1024);
  k_f2b<<<4096, 256, 0, stream>>>(Wih1f, wih1, 4096 * 1024);
  k_f2b<<<4096, 256, 0, stream>>>(Whh1f, whh1, 4096 * 1024);
  k_f2b<<<32, 256, 0, stream>>>(W1f, w1b, 32 * 1024);
  k_badd<<<16, 256, 0, stream>>>(bih0, bhh0, b0c, 4096);
  k_badd<<<16, 256, 0, stream>>>(bih1, bhh1, b1c, 4096);
  k_embed<<<(8 * NB) / 4, 256, 0, stream>>>(obs, Wemb, bemb, emb);

  bf16* h0buf[2] = {h0a, h0b};
  bf16* h1buf[2] = {h1a, h1b};
  float* preds = (float*)d_out;

  for (int t = 0; t < 20; ++t) {
    const bf16* xin;
    if (t < 8)       xin = emb + (size_t)t * NB * NE;
    else if (t == 8) xin = emb + (size_t)7 * NB * NE;  // curr_emb(0) == embed(obs[-1])
    else             xin = cemb;
    int cu = t & 1, pv = cu ^ 1;
    int kh = (t == 0) ? 0 : NH;  // h,c start at zero: skip recurrent K and c read at t=0
    k_cell<<<512, 512, 0, stream>>>(xin, NE, NE, h0buf[pv], kh,
                                    wih0, whh0, b0c, c0, h0buf[cu], t == 0);
    k_cell<<<512, 512, 0, stream>>>(h0buf[cu], NH, NH, h1buf[pv], kh,
                                    wih1, whh1, b1c, c1, h1buf[cu], t == 0);
    if (t >= 8) {
      int p = t - 8;
      const float* cin = (p == 0) ? (obs + (size_t)7 * NB * 2) : curr;
      k_mlp<<<NB / 4, 256, 0, stream>>>(h1buf[cu], w1b, b1m, W2, b2, W3, b3,
                                        cin, curr, preds + (size_t)p * NB * 2,
                                        Wemb, bemb, cemb);
    }
  }
}